// Round 7
// baseline (4025.324 us; speedup 1.0000x reference)
//
#include <hip/hip_runtime.h>
#include <hip/hip_bf16.h>

// BinaryTreeLSTM  B=64, L=1024, IN_DIM=300, MEM=256 — v7 "mono-kernel".
// One persistent kernel (1024 blocks = 256 CU x 4, residency-guaranteed via
// __launch_bounds__(256,4) + 32KB LDS) runs: pack+conv phase -> leaf GEMM ->
// 10 tree levels, separated by device-scope atomic grid barriers.
// GEMM tile core is v6 verbatim (conflict-free both-sides swizzle, 2-buf LDS,
// global_load_lds(16B), gate-deinterleaved fused epilogue).
// Barrier counters live in d_ws, zeroed by hipMemsetAsync each call.

#define NBLK 1024

typedef __attribute__((ext_vector_type(8))) short bf16x8;
typedef __attribute__((ext_vector_type(4))) float f32x4;

__device__ __forceinline__ float fsig(float x)  { return 1.f / (1.f + __expf(-x)); }
__device__ __forceinline__ float ftanh(float x) { return 1.f - 2.f / (__expf(2.f * x) + 1.f); }
__device__ __forceinline__ ushort f2bf(float x) {
    __hip_bfloat16 b = __float2bfloat16(x);
    return *reinterpret_cast<ushort*>(&b);
}

__device__ __forceinline__ void gld_lds16(const void* g, void* l) {
    __builtin_amdgcn_global_load_lds((const __attribute__((address_space(1))) void*)g,
                                     (__attribute__((address_space(3))) void*)l, 16, 0, 0);
}

__device__ __forceinline__ void grid_barrier(unsigned* ctr, int b) {
    __syncthreads();
    if (threadIdx.x == 0) {
        __threadfence();   // release: block's global writes -> device scope
        __hip_atomic_fetch_add(ctr + b, 1u, __ATOMIC_ACQ_REL, __HIP_MEMORY_SCOPE_AGENT);
        while (__hip_atomic_load(ctr + b, __ATOMIC_ACQUIRE, __HIP_MEMORY_SCOPE_AGENT)
               < (unsigned)NBLK)
            __builtin_amdgcn_s_sleep(8);
        __threadfence();
    }
    __syncthreads();
}

// ---------------- v6 GEMM tile core (verified) ----------------
// block tile 128 rows x (128/NG) o-cols x NG gates, 4 waves, wave 64r x 64G.
// MODE 0 = leaf (NG=2). MODE 1 = level; if hf_out != nullptr, h stored fp32.

template<int NG, int HALVES, int MODE>
__device__ __forceinline__ void gemm_tile(
    ushort* AsL, ushort* BsL,              // LDS [2][4096] each
    const ushort* __restrict__ A,          // (M, HALVES*32) bf16 row-major
    const ushort* __restrict__ Wb,         // packed weights
    const float* __restrict__ bp,          // (NG*256)
    const float* __restrict__ Cprev,       // (M, 512) fp32, levels only
    float* __restrict__ c_out,             // (M, 256) fp32
    ushort* __restrict__ h_out,            // (M, 256) bf16
    float* __restrict__ hf_out,            // (M, 256) fp32 (last level)
    int rowBlk, int o0, int M)
{
    constexpr int K = HALVES * 32;
    constexpr int OW = 128 / NG;
    constexpr size_t BSTR = (size_t)NG * 1024 * 8;

    const int tid = threadIdx.x;
    const int wid = tid >> 6, ln = tid & 63;
    const int lq = ln >> 4, lr = ln & 15;
    const int wm = wid >> 1, wn = wid & 1;

    f32x4 acc[4][4];
#pragma unroll
    for (int m = 0; m < 4; ++m)
#pragma unroll
        for (int f = 0; f < 4; ++f) acc[m][f] = f32x4{0.f, 0.f, 0.f, 0.f};

    const int ar0 = tid >> 2,  as0 = tid & 3;
    const int ar1 = ar0 + 64;
    const int aq0 = (as0 - ((ar0 >> 1) & 3)) & 3;
    const int aq1 = (as0 - ((ar1 >> 1) & 3)) & 3;
    const ushort* aP0 = A + (size_t)min(rowBlk + ar0, M - 1) * K + aq0 * 8;
    const ushort* aP1 = A + (size_t)min(rowBlk + ar1, M - 1) * K + aq1 * 8;
    const int bj0 = tid >> 2,        bs0 = tid & 3;
    const int bj1 = (tid + 256) >> 2;
    const int bg0 = bj0 / OW, bo0 = o0 + (bj0 & (OW - 1));
    const int bg1 = bj1 / OW, bo1 = o0 + (bj1 & (OW - 1));
    const ushort* bP0 = Wb + ((size_t)bg0 * 1024 + bo0 * 4 + bs0) * 8;
    const ushort* bP1 = Wb + ((size_t)bg1 * 1024 + bo1 * 4 + bs0) * 8;

    const int aSw = (lq + ((lr >> 1) & 3)) & 3;
    const int bSw = lq ^ ((lr >> 1) & 3);
    int aOff[4];
#pragma unroll
    for (int m = 0; m < 4; ++m)
        aOff[m] = ((wm * 64 + m * 16 + lr) * 4 + aSw) * 8;
    int bOff[4];
#pragma unroll
    for (int f = 0; f < 4; ++f)
        bOff[f] = ((f * 32 + wn * 16 + lr) * 4 + bSw) * 8;

    gld_lds16(aP0, AsL + tid * 8);
    gld_lds16(aP1, AsL + (tid + 256) * 8);
    gld_lds16(bP0, BsL + tid * 8);
    gld_lds16(bP1, BsL + (tid + 256) * 8);

#pragma unroll
    for (int h = 0; h < HALVES; ++h) {
        __syncthreads();               // drains vmcnt -> buf[cur] staged
        const int cur = h & 1;
        const ushort* Ac = AsL + cur * 4096;
        const ushort* Bc = BsL + cur * 4096;
        if (h + 1 < HALVES) {
            ushort* An = AsL + (cur ^ 1) * 4096;
            ushort* Bn = BsL + (cur ^ 1) * 4096;
            gld_lds16(aP0 + (size_t)(h + 1) * 32, An + tid * 8);
            gld_lds16(aP1 + (size_t)(h + 1) * 32, An + (tid + 256) * 8);
            gld_lds16(bP0 + (size_t)(h + 1) * BSTR, Bn + tid * 8);
            gld_lds16(bP1 + (size_t)(h + 1) * BSTR, Bn + (tid + 256) * 8);
        }
        bf16x8 a[4];
#pragma unroll
        for (int m = 0; m < 4; ++m)
            a[m] = *(const bf16x8*)(Ac + aOff[m]);
#pragma unroll
        for (int f = 0; f < 4; ++f) {
            bf16x8 b = *(const bf16x8*)(Bc + bOff[f]);
#pragma unroll
            for (int m = 0; m < 4; ++m)
                acc[m][f] = __builtin_amdgcn_mfma_f32_16x16x32_bf16(a[m], b, acc[m][f], 0, 0, 0);
        }
    }

#pragma unroll
    for (int m = 0; m < 4; ++m) {
        const int row0 = rowBlk + wm * 64 + m * 16 + lq * 4;
        if constexpr (MODE == 0) {
#pragma unroll
            for (int ob = 0; ob < 2; ++ob) {
                const int col = o0 + ob * 32 + wn * 16 + lr;
                const float bc = bp[col], bo = bp[256 + col];
#pragma unroll
                for (int j = 0; j < 4; ++j) {
                    int row = row0 + j;
                    if (row < M) {
                        float cv = acc[m][ob][j] + bc;
                        float ov = acc[m][2 + ob][j] + bo;
                        c_out[(size_t)row * 256 + col] = cv;
                        h_out[(size_t)row * 256 + col] = f2bf(fsig(ov) * ftanh(cv));
                    }
                }
            }
        } else {
            const int col = o0 + wn * 16 + lr;
            const float bi  = bp[col],       blf = bp[256 + col];
            const float brf = bp[512 + col], bu  = bp[768 + col];
#pragma unroll
            for (int j = 0; j < 4; ++j) {
                int row = row0 + j;
                if (row < M) {
                    float gi = fsig(acc[m][0][j] + bi);
                    float lf = fsig(acc[m][1][j] + blf);
                    float rf = fsig(acc[m][2][j] + brf);
                    float gu = ftanh(acc[m][3][j] + bu);
                    float lc = Cprev[(size_t)row * 512 + col];
                    float rc = Cprev[(size_t)row * 512 + 256 + col];
                    float cv = gi * gu + lf * lc + rf * rc;
                    float hv = ftanh(cv);
                    c_out[(size_t)row * 256 + col] = cv;
                    if (hf_out) hf_out[(size_t)row * 256 + col] = hv;
                    else        h_out[(size_t)row * 256 + col] = f2bf(hv);
                }
            }
        }
    }
}

// ---------------- mono-kernel ----------------

__global__ __launch_bounds__(256, 4)
void tree_lstm(const float* __restrict__ embs,
               const float* __restrict__ Wcx, const float* __restrict__ bcx,
               const float* __restrict__ Wox, const float* __restrict__ box,
               const float* __restrict__ Wl,  const float* __restrict__ bl,
               const float* __restrict__ Wr,  const float* __restrict__ br,
               ushort* Wb2, ushort* WbL, float* bp2, float* bpL,
               ushort* embsB, float* c0, ushort* h0,
               float* cA, ushort* hA, float* cB, ushort* hB,
               float* dout, unsigned* ctr)
{
    __shared__ __align__(16) ushort As[2][4096];
    __shared__ __align__(16) ushort Bs[2][4096];

    const int tid = threadIdx.x;
    const int gid = blockIdx.x * 256 + tid;

    // ---- phase 0: pack level + pack leaf + biases + embs conversion
    for (int i = gid; i < 524288; i += NBLK * 256) {
        int e = i & 7, slot = (i >> 3) & 3, o = (i >> 5) & 255;
        int g = (i >> 13) & 3, t = i >> 15;
        int q = slot ^ ((o >> 1) & 3);
        int k = t * 32 + q * 8 + e;
        float v = (k < 256) ? Wl[(g * 256 + o) * 256 + k]
                            : Wr[(g * 256 + o) * 256 + (k - 256)];
        Wb2[i] = f2bf(v);
    }
    if (gid < 163840) {
        int e = gid & 7, slot = (gid >> 3) & 3, o = (gid >> 5) & 255;
        int g = (gid >> 13) & 1, t = gid >> 14;
        int q = slot ^ ((o >> 1) & 3);
        int k = t * 32 + q * 8 + e;
        float v = 0.f;
        if (k < 300) v = g ? Wox[o * 300 + k] : Wcx[o * 300 + k];
        WbL[gid] = f2bf(v);
    }
    if (gid < 1024) bp2[gid] = bl[gid] + br[gid];
    if (gid < 512) {
        int g = gid >> 8, o = gid & 255;
        bpL[gid] = g ? box[o] : bcx[o];
    }
    for (int i = gid; i < 65536 * 80; i += NBLK * 256) {
        int row = i / 80;
        int k = (i - row * 80) * 4;
        float4 v = make_float4(0.f, 0.f, 0.f, 0.f);
        if (k < 300) v = *(const float4*)(embs + (size_t)row * 300 + k);
        ushort4 o4;
        o4.x = f2bf(v.x); o4.y = f2bf(v.y); o4.z = f2bf(v.z); o4.w = f2bf(v.w);
        *(ushort4*)(embsB + (size_t)row * 320 + k) = o4;
    }
    grid_barrier(ctr, 0);

    // ---- phase 1: leaf GEMM  (65536,320)@(320,2*256) -> c0 fp32, h0 bf16
    for (int t = blockIdx.x; t < 2048; t += NBLK)
        gemm_tile<2, 10, 0>(&As[0][0], &Bs[0][0], embsB, WbL, bpL, nullptr,
                            c0, h0, nullptr, (t >> 2) * 128, (t & 3) * 64, 65536);
    grid_barrier(ctr, 1);

    // ---- phases 2..11: tree levels
    const ushort* hin = h0;
    const float*  cin = c0;
    int flip = 0;
    for (int lvl = 0; lvl < 10; ++lvl) {
        const int np = 512 >> lvl;
        const int M = np * 64;
        const int ntile = ((M + 127) >> 7) * 8;
        const bool last = (lvl == 9);
        float*  co = last ? dout : (flip ? cB : cA);
        ushort* ho = flip ? hB : hA;
        float*  hf = last ? (dout + 64 * 256) : nullptr;
        for (int t = blockIdx.x; t < ntile; t += NBLK)
            gemm_tile<4, 16, 1>(&As[0][0], &Bs[0][0], hin, Wb2, bp2, cin,
                                co, ho, hf, (t >> 3) * 128, (t & 7) * 32, M);
        if (!last) {
            grid_barrier(ctr, 2 + lvl);
            hin = ho; cin = co; flip ^= 1;
        }
    }
}

// ---------------- host ----------------

extern "C" void kernel_launch(void* const* d_in, const int* in_sizes, int n_in,
                              void* d_out, int out_size, void* d_ws, size_t ws_size,
                              hipStream_t stream)
{
    const float* embs = (const float*)d_in[0];
    const float* Wcx  = (const float*)d_in[1];
    const float* bcx  = (const float*)d_in[2];
    const float* Wox  = (const float*)d_in[3];
    const float* box  = (const float*)d_in[4];
    const float* Wl   = (const float*)d_in[5];
    const float* bl   = (const float*)d_in[6];
    const float* Wr   = (const float*)d_in[7];
    const float* br   = (const float*)d_in[8];

    char* p = (char*)d_ws;
    unsigned* ctr = (unsigned*)p;  p += 256;
    ushort* Wb2 = (ushort*)p;  p += (size_t)524288 * 2;
    ushort* WbL = (ushort*)p;  p += (size_t)163840 * 2;
    float*  bp2 = (float*)p;   p += 1024 * 4;
    float*  bpL = (float*)p;   p += 512 * 4;
    float*  c0  = (float*)p;   p += (size_t)65536 * 256 * 4;   // 64 MB
    ushort* h0  = (ushort*)p;  p += (size_t)65536 * 256 * 2;   // 32 MB
    char* X = p;
    ushort* embsB = (ushort*)X;                                 // 40 MB (dead after leaf)
    float*  cA = (float*)X;                                     // 32 MB
    ushort* hA = (ushort*)(X + (size_t)32768 * 256 * 4);        // 16 MB
    float*  cB = (float*)(X + (size_t)48 * 1024 * 1024);        // 16 MB
    ushort* hB = (ushort*)(X + (size_t)64 * 1024 * 1024);       // 8 MB

    hipMemsetAsync(ctr, 0, 256, stream);   // reset grid-barrier counters

    tree_lstm<<<NBLK, 256, 0, stream>>>(
        embs, Wcx, bcx, Wox, box, Wl, bl, Wr, br,
        Wb2, WbL, bp2, bpL, embsB, c0, h0, cA, hA, cB, hB,
        (float*)d_out, ctr);
}

// Round 8
// 650.683 us; speedup vs baseline: 6.1863x; 6.1863x over previous
//
#include <hip/hip_runtime.h>
#include <hip/hip_bf16.h>

// BinaryTreeLSTM  B=64, L=1024, IN_DIM=300, MEM=256 — v8.
// 6 launches: prep (fused packs+conv) -> leaf -> L512 -> L256 -> L128 -> tail.
// Big-level GEMM = v6 core (verified conflict-free both-sides swizzle).
// Tail = out-np 64..1 in ONE kernel, 64 independent blocks (one per batch),
// h in LDS (XOR chunk swizzle), c in block-private global scratch, B-frags
// direct global->VGPR from packed Wb2 (L2-hot). No grid sync anywhere.

typedef __attribute__((ext_vector_type(8))) short bf16x8;
typedef __attribute__((ext_vector_type(4))) float f32x4;

__device__ __forceinline__ float fsig(float x)  { return 1.f / (1.f + __expf(-x)); }
__device__ __forceinline__ float ftanh(float x) { return 1.f - 2.f / (__expf(2.f * x) + 1.f); }
__device__ __forceinline__ ushort f2bf(float x) {
    __hip_bfloat16 b = __float2bfloat16(x);
    return *reinterpret_cast<ushort*>(&b);
}

__device__ __forceinline__ void gld_lds16(const void* g, void* l) {
    __builtin_amdgcn_global_load_lds((const __attribute__((address_space(1))) void*)g,
                                     (__attribute__((address_space(3))) void*)l, 16, 0, 0);
}

// ---------------- prep: pack level + pack leaf + biases + embs->bf16 ----------------
__global__ void prep(const float* __restrict__ Wl,  const float* __restrict__ Wr,
                     const float* __restrict__ bl,  const float* __restrict__ br,
                     const float* __restrict__ Wcx, const float* __restrict__ Wox,
                     const float* __restrict__ bcx, const float* __restrict__ box,
                     const float* __restrict__ embs,
                     ushort* __restrict__ Wb2, ushort* __restrict__ WbL,
                     float* __restrict__ bp2, float* __restrict__ bpL,
                     ushort* __restrict__ embsB)
{
    const int gid = blockIdx.x * 256 + threadIdx.x;     // 1024 blocks -> 262144
    for (int i = gid; i < 524288; i += 262144) {
        int e = i & 7, slot = (i >> 3) & 3, o = (i >> 5) & 255;
        int g = (i >> 13) & 3, t = i >> 15;
        int q = slot ^ ((o >> 1) & 3);
        int k = t * 32 + q * 8 + e;
        float v = (k < 256) ? Wl[(g * 256 + o) * 256 + k]
                            : Wr[(g * 256 + o) * 256 + (k - 256)];
        Wb2[i] = f2bf(v);
    }
    if (gid < 163840) {
        int e = gid & 7, slot = (gid >> 3) & 3, o = (gid >> 5) & 255;
        int g = (gid >> 13) & 1, t = gid >> 14;
        int q = slot ^ ((o >> 1) & 3);
        int k = t * 32 + q * 8 + e;
        float v = 0.f;
        if (k < 300) v = g ? Wox[o * 300 + k] : Wcx[o * 300 + k];
        WbL[gid] = f2bf(v);
    }
    if (gid < 1024) bp2[gid] = bl[gid] + br[gid];
    if (gid < 512) {
        int g = gid >> 8, o = gid & 255;
        bpL[gid] = g ? box[o] : bcx[o];
    }
    for (int i = gid; i < 65536 * 80; i += 262144) {
        int row = i / 80;
        int k = (i - row * 80) * 4;
        float4 v = make_float4(0.f, 0.f, 0.f, 0.f);
        if (k < 300) v = *(const float4*)(embs + (size_t)row * 300 + k);
        ushort4 o4;
        o4.x = f2bf(v.x); o4.y = f2bf(v.y); o4.z = f2bf(v.z); o4.w = f2bf(v.w);
        *(ushort4*)(embsB + (size_t)row * 320 + k) = o4;
    }
}

// ---------------- v6 big-level GEMM (verified) ----------------
// block 128 rows x (128/NG) o-cols x NG gates, 4 waves, wave 64r x 64G.
// MODE 0 = leaf (NG=2), 1 = level (h->bf16).

template<int NG, int HALVES, int MODE>
__global__ __launch_bounds__(256, 4)
void mfma_gemm(const ushort* __restrict__ A,
               const ushort* __restrict__ Wb,
               const float* __restrict__ bp,
               const float* __restrict__ Cprev,
               float* __restrict__ c_out,
               ushort* __restrict__ h_out,
               int M)
{
    constexpr int K = HALVES * 32;
    constexpr int OW = 128 / NG;
    __shared__ __align__(16) ushort As[2][512 * 8];
    __shared__ __align__(16) ushort Bs[2][512 * 8];

    const int tid = threadIdx.x;
    const int wid = tid >> 6, ln = tid & 63;
    const int lq = ln >> 4, lr = ln & 15;
    const int wm = wid >> 1, wn = wid & 1;
    const int rowBlk = blockIdx.x * 128;
    const int o0 = blockIdx.y * OW;

    f32x4 acc[4][4];
#pragma unroll
    for (int m = 0; m < 4; ++m)
#pragma unroll
        for (int f = 0; f < 4; ++f) acc[m][f] = f32x4{0.f, 0.f, 0.f, 0.f};

    const int ar0 = tid >> 2,  as0 = tid & 3;
    const int ar1 = ar0 + 64;
    const int aq0 = (as0 - ((ar0 >> 1) & 3)) & 3;
    const int aq1 = (as0 - ((ar1 >> 1) & 3)) & 3;
    const ushort* aP0 = A + (size_t)min(rowBlk + ar0, M - 1) * K + aq0 * 8;
    const ushort* aP1 = A + (size_t)min(rowBlk + ar1, M - 1) * K + aq1 * 8;
    const int bj0 = tid >> 2,        bs0 = tid & 3;
    const int bj1 = (tid + 256) >> 2;
    const int bg0 = bj0 / OW, bo0 = o0 + (bj0 & (OW - 1));
    const int bg1 = bj1 / OW, bo1 = o0 + (bj1 & (OW - 1));
    const ushort* bP0 = Wb + ((size_t)bg0 * 1024 + bo0 * 4 + bs0) * 8;
    const ushort* bP1 = Wb + ((size_t)bg1 * 1024 + bo1 * 4 + bs0) * 8;
    constexpr size_t BSTR = (size_t)NG * 1024 * 8;

    const int aSw = (lq + ((lr >> 1) & 3)) & 3;
    const int bSw = lq ^ ((lr >> 1) & 3);
    int aOff[4];
#pragma unroll
    for (int m = 0; m < 4; ++m)
        aOff[m] = ((wm * 64 + m * 16 + lr) * 4 + aSw) * 8;
    int bOff[4];
#pragma unroll
    for (int f = 0; f < 4; ++f)
        bOff[f] = ((f * 32 + wn * 16 + lr) * 4 + bSw) * 8;

    gld_lds16(aP0, &As[0][tid * 8]);
    gld_lds16(aP1, &As[0][(tid + 256) * 8]);
    gld_lds16(bP0, &Bs[0][tid * 8]);
    gld_lds16(bP1, &Bs[0][(tid + 256) * 8]);

#pragma unroll
    for (int h = 0; h < HALVES; ++h) {
        __syncthreads();
        const int cur = h & 1;
        if (h + 1 < HALVES) {
            gld_lds16(aP0 + (size_t)(h + 1) * 32, &As[cur ^ 1][tid * 8]);
            gld_lds16(aP1 + (size_t)(h + 1) * 32, &As[cur ^ 1][(tid + 256) * 8]);
            gld_lds16(bP0 + (size_t)(h + 1) * BSTR, &Bs[cur ^ 1][tid * 8]);
            gld_lds16(bP1 + (size_t)(h + 1) * BSTR, &Bs[cur ^ 1][(tid + 256) * 8]);
        }
        bf16x8 a[4];
#pragma unroll
        for (int m = 0; m < 4; ++m)
            a[m] = *(const bf16x8*)&As[cur][aOff[m]];
#pragma unroll
        for (int f = 0; f < 4; ++f) {
            bf16x8 b = *(const bf16x8*)&Bs[cur][bOff[f]];
#pragma unroll
            for (int m = 0; m < 4; ++m)
                acc[m][f] = __builtin_amdgcn_mfma_f32_16x16x32_bf16(a[m], b, acc[m][f], 0, 0, 0);
        }
    }

#pragma unroll
    for (int m = 0; m < 4; ++m) {
        const int row0 = rowBlk + wm * 64 + m * 16 + lq * 4;
        if constexpr (MODE == 0) {
#pragma unroll
            for (int ob = 0; ob < 2; ++ob) {
                const int col = o0 + ob * 32 + wn * 16 + lr;
                const float bc = bp[col], bo = bp[256 + col];
#pragma unroll
                for (int j = 0; j < 4; ++j) {
                    int row = row0 + j;
                    if (row < M) {
                        float cv = acc[m][ob][j] + bc;
                        float ov = acc[m][2 + ob][j] + bo;
                        c_out[(size_t)row * 256 + col] = cv;
                        h_out[(size_t)row * 256 + col] = f2bf(fsig(ov) * ftanh(cv));
                    }
                }
            }
        } else {
            const int col = o0 + wn * 16 + lr;
            const float bi  = bp[col],       blf = bp[256 + col];
            const float brf = bp[512 + col], bu  = bp[768 + col];
#pragma unroll
            for (int j = 0; j < 4; ++j) {
                int row = row0 + j;
                if (row < M) {
                    float gi = fsig(acc[m][0][j] + bi);
                    float lf = fsig(acc[m][1][j] + blf);
                    float rf = fsig(acc[m][2][j] + brf);
                    float gu = ftanh(acc[m][3][j] + bu);
                    float lc = Cprev[(size_t)row * 512 + col];
                    float rc = Cprev[(size_t)row * 512 + 256 + col];
                    float cv = gi * gu + lf * lc + rf * rc;
                    c_out[(size_t)row * 256 + col] = cv;
                    h_out[(size_t)row * 256 + col] = f2bf(ftanh(cv));
                }
            }
        }
    }
}

// ---------------- tail: out-np 64..1, one block per batch ----------------
// A (h) in LDS, chunk-swizzled: chunk(pr,pc) stored at pr*256 + (pc^((pr>>1)&7))*8.
// B-frags direct from packed Wb2 (same layout as v6: chunk (ks*4+g)*1024+o*4+slot,
// content q = slot ^ ((o>>1)&3)).

template<int MC, bool LAST>
__device__ __forceinline__ void tail_level(
    const ushort* inb, ushort* outb,
    const ushort* __restrict__ Wb, const float* __restrict__ bp,
    const float* __restrict__ cprev, float* __restrict__ cout_,
    float* __restrict__ dout, int b, int npo)
{
    const int tid = threadIdx.x;
    const int wid = tid >> 6, ln = tid & 63;
    const int lq = ln >> 4, lr = ln & 15;

#pragma unroll
    for (int oh = 0; oh < 2; ++oh) {
        const int ob = wid * 64 + oh * 32;
        f32x4 acc[MC][2][4];
#pragma unroll
        for (int m = 0; m < MC; ++m)
#pragma unroll
            for (int of = 0; of < 2; ++of)
#pragma unroll
                for (int g = 0; g < 4; ++g) acc[m][of][g] = f32x4{0.f, 0.f, 0.f, 0.f};

        int o_[2], sl_[2];
#pragma unroll
        for (int of = 0; of < 2; ++of) {
            o_[of] = ob + of * 16 + lr;
            sl_[of] = lq ^ ((o_[of] >> 1) & 3);
        }

#pragma unroll
        for (int ks = 0; ks < 16; ++ks) {
            bf16x8 bfr[2][4];
#pragma unroll
            for (int of = 0; of < 2; ++of)
#pragma unroll
                for (int g = 0; g < 4; ++g)
                    bfr[of][g] = *(const bf16x8*)(Wb +
                        ((size_t)(ks * 4 + g) * 1024 + o_[of] * 4 + sl_[of]) * 8);
            bf16x8 a[MC];
#pragma unroll
            for (int m = 0; m < MC; ++m) {
                int r = m * 16 + lr;
                int pr = 2 * r + (ks >> 3);
                int pc = lq + (ks & 7) * 4;
                a[m] = *(const bf16x8*)&inb[pr * 256 + ((pc ^ ((pr >> 1) & 7)) * 8)];
            }
#pragma unroll
            for (int of = 0; of < 2; ++of)
#pragma unroll
                for (int g = 0; g < 4; ++g)
#pragma unroll
                    for (int m = 0; m < MC; ++m)
                        acc[m][of][g] = __builtin_amdgcn_mfma_f32_16x16x32_bf16(
                            a[m], bfr[of][g], acc[m][of][g], 0, 0, 0);
        }

#pragma unroll
        for (int m = 0; m < MC; ++m) {
#pragma unroll
            for (int of = 0; of < 2; ++of) {
                const int col = ob + of * 16 + lr;
                const float bi  = bp[col],       blf = bp[256 + col];
                const float brf = bp[512 + col], bu  = bp[768 + col];
#pragma unroll
                for (int j = 0; j < 4; ++j) {
                    int row = m * 16 + lq * 4 + j;
                    if (row < npo) {
                        float gi = fsig(acc[m][of][0][j] + bi);
                        float lf = fsig(acc[m][of][1][j] + blf);
                        float rf = fsig(acc[m][of][2][j] + brf);
                        float gu = ftanh(acc[m][of][3][j] + bu);
                        float lc = cprev[(size_t)(2 * row) * 256 + col];
                        float rc = cprev[(size_t)(2 * row + 1) * 256 + col];
                        float cv = gi * gu + lf * lc + rf * rc;
                        float hv = ftanh(cv);
                        if (LAST) {
                            dout[b * 256 + col] = cv;
                            dout[16384 + b * 256 + col] = hv;
                        } else {
                            cout_[row * 256 + col] = cv;
                            outb[row * 256 + (((col >> 3) ^ ((row >> 1) & 7)) * 8) + (col & 7)] = f2bf(hv);
                        }
                    }
                }
            }
        }
    }
}

__global__ __launch_bounds__(256, 1)
void tail_lstm(const ushort* __restrict__ hin,   // (8192,256) bf16: 64 x 128 nodes
               const float* __restrict__ cin,    // (8192,256) fp32
               const ushort* __restrict__ Wb,    // packed level weights
               const float* __restrict__ bp,     // (1024)
               float* __restrict__ cscr,         // 2 x 64 x 64 x 256 fp32 ping
               float* __restrict__ dout)
{
    __shared__ __align__(16) ushort P0[128 * 256];   // 64 KB
    __shared__ __align__(16) ushort P1[64 * 256];    // 32 KB

    const int b = blockIdx.x;
    const int tid = threadIdx.x;

    for (int ct = tid; ct < 4096; ct += 256) {
        int pr = ct >> 5, pc = ct & 31;
        bf16x8 v = *(const bf16x8*)(hin + ((size_t)(b * 128 + pr) * 256 + pc * 8));
        *(bf16x8*)&P0[pr * 256 + ((pc ^ ((pr >> 1) & 7)) * 8)] = v;
    }
    __syncthreads();

    float* c0p = cscr + (size_t)b * 64 * 256;
    float* c1p = cscr + (size_t)(64 + b) * 64 * 256;
    const float* cin_b = cin + (size_t)b * 128 * 256;

    tail_level<4, false>(P0, P1, Wb, bp, cin_b, c0p, nullptr, b, 64);
    __syncthreads();
    tail_level<2, false>(P1, P0, Wb, bp, c0p, c1p, nullptr, b, 32);
    __syncthreads();
    tail_level<1, false>(P0, P1, Wb, bp, c1p, c0p, nullptr, b, 16);
    __syncthreads();
    tail_level<1, false>(P1, P0, Wb, bp, c0p, c1p, nullptr, b, 8);
    __syncthreads();
    tail_level<1, false>(P0, P1, Wb, bp, c1p, c0p, nullptr, b, 4);
    __syncthreads();
    tail_level<1, false>(P1, P0, Wb, bp, c0p, c1p, nullptr, b, 2);
    __syncthreads();
    tail_level<1, true>(P0, P1, Wb, bp, c1p, nullptr, dout, b, 1);
}

// ---------------- host ----------------

extern "C" void kernel_launch(void* const* d_in, const int* in_sizes, int n_in,
                              void* d_out, int out_size, void* d_ws, size_t ws_size,
                              hipStream_t stream)
{
    const float* embs = (const float*)d_in[0];
    const float* Wcx  = (const float*)d_in[1];
    const float* bcx  = (const float*)d_in[2];
    const float* Wox  = (const float*)d_in[3];
    const float* box  = (const float*)d_in[4];
    const float* Wl   = (const float*)d_in[5];
    const float* bl   = (const float*)d_in[6];
    const float* Wr   = (const float*)d_in[7];
    const float* br   = (const float*)d_in[8];

    char* p = (char*)d_ws;
    ushort* Wb2 = (ushort*)p;  p += (size_t)524288 * 2;
    ushort* WbL = (ushort*)p;  p += (size_t)163840 * 2;
    float*  bp2 = (float*)p;   p += 1024 * 4;
    float*  bpL = (float*)p;   p += 512 * 4;
    float*  c0  = (float*)p;   p += (size_t)65536 * 256 * 4;   // 64 MB
    float*  cscr= (float*)p;                                    // reuse h0 region
    ushort* h0  = (ushort*)p;  p += (size_t)65536 * 256 * 2;   // 32 MB (h0 after lvl512 is dead -> cscr ok? no: cscr used in tail, h0 dead after L512 ✓)
    char* X = p;
    ushort* embsB = (ushort*)X;                                 // 40 MB (dead after leaf)
    float*  cA = (float*)X;                                     // 32 MB
    ushort* hA = (ushort*)(X + (size_t)32768 * 256 * 4);        // 16 MB
    float*  cB = (float*)(X + (size_t)48 * 1024 * 1024);        // 16 MB
    ushort* hB = (ushort*)(X + (size_t)64 * 1024 * 1024);       // 8 MB

    prep<<<1024, 256, 0, stream>>>(Wl, Wr, bl, br, Wcx, Wox, bcx, box, embs,
                                   Wb2, WbL, bp2, bpL, embsB);

    // leaf: (65536,320) @ (320, 2*256) -> c0 fp32, h0 bf16
    mfma_gemm<2, 10, 0><<<dim3(512, 4), 256, 0, stream>>>(
        embsB, WbL, bpL, nullptr, c0, h0, 65536);

    // out-np=512: in h0 (32768,512), c0 -> cA,hA
    mfma_gemm<4, 16, 1><<<dim3(256, 8), 256, 0, stream>>>(
        h0, Wb2, bp2, c0, cA, hA, 32768);
    // out-np=256: in hA (16384,512), cA -> cB,hB
    mfma_gemm<4, 16, 1><<<dim3(128, 8), 256, 0, stream>>>(
        hA, Wb2, bp2, cA, cB, hB, 16384);
    // out-np=128: in hB (8192,512), cB -> cA,hA
    mfma_gemm<4, 16, 1><<<dim3(64, 8), 256, 0, stream>>>(
        hB, Wb2, bp2, cB, cA, hA, 8192);

    // tail: out-np 64..1 (input hA (8192,256), cA); cscr reuses h0 region (dead)
    tail_lstm<<<64, 256, 0, stream>>>(
        hA, cA, Wb2, bp2, cscr, (float*)d_out);
}

// Round 9
// 472.370 us; speedup vs baseline: 8.5215x; 1.3775x over previous
//
#include <hip/hip_runtime.h>
#include <hip/hip_bf16.h>

// BinaryTreeLSTM  B=64, L=1024, IN_DIM=300, MEM=256 — v9.
// 6 launches: prep -> leaf -> L512 -> L256 -> L128 -> tail(64..1).
// Big-level GEMM = v6 core (verified). Tail rewritten vs v8: 512 threads,
// wave w owns o in [32w,32w+32) x 4 gates -> acc <=128 VGPR, no spills.

typedef __attribute__((ext_vector_type(8))) short bf16x8;
typedef __attribute__((ext_vector_type(4))) float f32x4;

__device__ __forceinline__ float fsig(float x)  { return 1.f / (1.f + __expf(-x)); }
__device__ __forceinline__ float ftanh(float x) { return 1.f - 2.f / (__expf(2.f * x) + 1.f); }
__device__ __forceinline__ ushort f2bf(float x) {
    __hip_bfloat16 b = __float2bfloat16(x);
    return *reinterpret_cast<ushort*>(&b);
}

__device__ __forceinline__ void gld_lds16(const void* g, void* l) {
    __builtin_amdgcn_global_load_lds((const __attribute__((address_space(1))) void*)g,
                                     (__attribute__((address_space(3))) void*)l, 16, 0, 0);
}

// ---------------- prep: pack level + pack leaf + biases + embs->bf16 ----------------
__global__ void prep(const float* __restrict__ Wl,  const float* __restrict__ Wr,
                     const float* __restrict__ bl,  const float* __restrict__ br,
                     const float* __restrict__ Wcx, const float* __restrict__ Wox,
                     const float* __restrict__ bcx, const float* __restrict__ box,
                     const float* __restrict__ embs,
                     ushort* __restrict__ Wb2, ushort* __restrict__ WbL,
                     float* __restrict__ bp2, float* __restrict__ bpL,
                     ushort* __restrict__ embsB)
{
    const int gid = blockIdx.x * 256 + threadIdx.x;     // 1024 blocks -> 262144
    for (int i = gid; i < 524288; i += 262144) {
        int e = i & 7, slot = (i >> 3) & 3, o = (i >> 5) & 255;
        int g = (i >> 13) & 3, t = i >> 15;
        int q = slot ^ ((o >> 1) & 3);
        int k = t * 32 + q * 8 + e;
        float v = (k < 256) ? Wl[(g * 256 + o) * 256 + k]
                            : Wr[(g * 256 + o) * 256 + (k - 256)];
        Wb2[i] = f2bf(v);
    }
    if (gid < 163840) {
        int e = gid & 7, slot = (gid >> 3) & 3, o = (gid >> 5) & 255;
        int g = (gid >> 13) & 1, t = gid >> 14;
        int q = slot ^ ((o >> 1) & 3);
        int k = t * 32 + q * 8 + e;
        float v = 0.f;
        if (k < 300) v = g ? Wox[o * 300 + k] : Wcx[o * 300 + k];
        WbL[gid] = f2bf(v);
    }
    if (gid < 1024) bp2[gid] = bl[gid] + br[gid];
    if (gid < 512) {
        int g = gid >> 8, o = gid & 255;
        bpL[gid] = g ? box[o] : bcx[o];
    }
    for (int i = gid; i < 65536 * 80; i += 262144) {
        int row = i / 80;
        int k = (i - row * 80) * 4;
        float4 v = make_float4(0.f, 0.f, 0.f, 0.f);
        if (k < 300) v = *(const float4*)(embs + (size_t)row * 300 + k);
        ushort4 o4;
        o4.x = f2bf(v.x); o4.y = f2bf(v.y); o4.z = f2bf(v.z); o4.w = f2bf(v.w);
        *(ushort4*)(embsB + (size_t)row * 320 + k) = o4;
    }
}

// ---------------- v6 big-level GEMM (verified) ----------------
template<int NG, int HALVES, int MODE>
__global__ __launch_bounds__(256, 4)
void mfma_gemm(const ushort* __restrict__ A,
               const ushort* __restrict__ Wb,
               const float* __restrict__ bp,
               const float* __restrict__ Cprev,
               float* __restrict__ c_out,
               ushort* __restrict__ h_out,
               int M)
{
    constexpr int K = HALVES * 32;
    constexpr int OW = 128 / NG;
    __shared__ __align__(16) ushort As[2][512 * 8];
    __shared__ __align__(16) ushort Bs[2][512 * 8];

    const int tid = threadIdx.x;
    const int wid = tid >> 6, ln = tid & 63;
    const int lq = ln >> 4, lr = ln & 15;
    const int wm = wid >> 1, wn = wid & 1;
    const int rowBlk = blockIdx.x * 128;
    const int o0 = blockIdx.y * OW;

    f32x4 acc[4][4];
#pragma unroll
    for (int m = 0; m < 4; ++m)
#pragma unroll
        for (int f = 0; f < 4; ++f) acc[m][f] = f32x4{0.f, 0.f, 0.f, 0.f};

    const int ar0 = tid >> 2,  as0 = tid & 3;
    const int ar1 = ar0 + 64;
    const int aq0 = (as0 - ((ar0 >> 1) & 3)) & 3;
    const int aq1 = (as0 - ((ar1 >> 1) & 3)) & 3;
    const ushort* aP0 = A + (size_t)min(rowBlk + ar0, M - 1) * K + aq0 * 8;
    const ushort* aP1 = A + (size_t)min(rowBlk + ar1, M - 1) * K + aq1 * 8;
    const int bj0 = tid >> 2,        bs0 = tid & 3;
    const int bj1 = (tid + 256) >> 2;
    const int bg0 = bj0 / OW, bo0 = o0 + (bj0 & (OW - 1));
    const int bg1 = bj1 / OW, bo1 = o0 + (bj1 & (OW - 1));
    const ushort* bP0 = Wb + ((size_t)bg0 * 1024 + bo0 * 4 + bs0) * 8;
    const ushort* bP1 = Wb + ((size_t)bg1 * 1024 + bo1 * 4 + bs0) * 8;
    constexpr size_t BSTR = (size_t)NG * 1024 * 8;

    const int aSw = (lq + ((lr >> 1) & 3)) & 3;
    const int bSw = lq ^ ((lr >> 1) & 3);
    int aOff[4];
#pragma unroll
    for (int m = 0; m < 4; ++m)
        aOff[m] = ((wm * 64 + m * 16 + lr) * 4 + aSw) * 8;
    int bOff[4];
#pragma unroll
    for (int f = 0; f < 4; ++f)
        bOff[f] = ((f * 32 + wn * 16 + lr) * 4 + bSw) * 8;

    gld_lds16(aP0, &As[0][tid * 8]);
    gld_lds16(aP1, &As[0][(tid + 256) * 8]);
    gld_lds16(bP0, &Bs[0][tid * 8]);
    gld_lds16(bP1, &Bs[0][(tid + 256) * 8]);

#pragma unroll
    for (int h = 0; h < HALVES; ++h) {
        __syncthreads();
        const int cur = h & 1;
        if (h + 1 < HALVES) {
            gld_lds16(aP0 + (size_t)(h + 1) * 32, &As[cur ^ 1][tid * 8]);
            gld_lds16(aP1 + (size_t)(h + 1) * 32, &As[cur ^ 1][(tid + 256) * 8]);
            gld_lds16(bP0 + (size_t)(h + 1) * BSTR, &Bs[cur ^ 1][tid * 8]);
            gld_lds16(bP1 + (size_t)(h + 1) * BSTR, &Bs[cur ^ 1][(tid + 256) * 8]);
        }
        bf16x8 a[4];
#pragma unroll
        for (int m = 0; m < 4; ++m)
            a[m] = *(const bf16x8*)&As[cur][aOff[m]];
#pragma unroll
        for (int f = 0; f < 4; ++f) {
            bf16x8 b = *(const bf16x8*)&Bs[cur][bOff[f]];
#pragma unroll
            for (int m = 0; m < 4; ++m)
                acc[m][f] = __builtin_amdgcn_mfma_f32_16x16x32_bf16(a[m], b, acc[m][f], 0, 0, 0);
        }
    }

#pragma unroll
    for (int m = 0; m < 4; ++m) {
        const int row0 = rowBlk + wm * 64 + m * 16 + lq * 4;
        if constexpr (MODE == 0) {
#pragma unroll
            for (int ob = 0; ob < 2; ++ob) {
                const int col = o0 + ob * 32 + wn * 16 + lr;
                const float bc = bp[col], bo = bp[256 + col];
#pragma unroll
                for (int j = 0; j < 4; ++j) {
                    int row = row0 + j;
                    if (row < M) {
                        float cv = acc[m][ob][j] + bc;
                        float ov = acc[m][2 + ob][j] + bo;
                        c_out[(size_t)row * 256 + col] = cv;
                        h_out[(size_t)row * 256 + col] = f2bf(fsig(ov) * ftanh(cv));
                    }
                }
            }
        } else {
            const int col = o0 + wn * 16 + lr;
            const float bi  = bp[col],       blf = bp[256 + col];
            const float brf = bp[512 + col], bu  = bp[768 + col];
#pragma unroll
            for (int j = 0; j < 4; ++j) {
                int row = row0 + j;
                if (row < M) {
                    float gi = fsig(acc[m][0][j] + bi);
                    float lf = fsig(acc[m][1][j] + blf);
                    float rf = fsig(acc[m][2][j] + brf);
                    float gu = ftanh(acc[m][3][j] + bu);
                    float lc = Cprev[(size_t)row * 512 + col];
                    float rc = Cprev[(size_t)row * 512 + 256 + col];
                    float cv = gi * gu + lf * lc + rf * rc;
                    c_out[(size_t)row * 256 + col] = cv;
                    h_out[(size_t)row * 256 + col] = f2bf(ftanh(cv));
                }
            }
        }
    }
}

// ---------------- tail: out-np 64..1, one block per batch, 512 threads ----------------
// Wave w owns o-cols [32w, 32w+32) x 4 gates.  acc[MC][2][4] <= 128 VGPR.
// h in LDS (XOR chunk swizzle, same as v8), c in block-private global scratch,
// B-frags direct global->VGPR from packed Wb2 (L2-hot), ks fully unrolled.

template<int MC, bool LAST>
__device__ __forceinline__ void tail_level(
    const ushort* inb, ushort* outb,
    const ushort* __restrict__ Wb, const float* __restrict__ bp,
    const float* __restrict__ cprev, float* __restrict__ cout_,
    float* __restrict__ dout, int b, int npo)
{
    const int tid = threadIdx.x;
    const int wid = tid >> 6, ln = tid & 63;    // wid 0..7
    const int lq = ln >> 4, lr = ln & 15;

    f32x4 acc[MC][2][4];
#pragma unroll
    for (int m = 0; m < MC; ++m)
#pragma unroll
        for (int of = 0; of < 2; ++of)
#pragma unroll
            for (int g = 0; g < 4; ++g) acc[m][of][g] = f32x4{0.f, 0.f, 0.f, 0.f};

    int o_[2], sl_[2];
#pragma unroll
    for (int of = 0; of < 2; ++of) {
        o_[of] = wid * 32 + of * 16 + lr;
        sl_[of] = lq ^ ((o_[of] >> 1) & 3);
    }

#pragma unroll
    for (int ks = 0; ks < 16; ++ks) {
        bf16x8 bfr[2][4];
#pragma unroll
        for (int of = 0; of < 2; ++of)
#pragma unroll
            for (int g = 0; g < 4; ++g)
                bfr[of][g] = *(const bf16x8*)(Wb +
                    ((size_t)(ks * 4 + g) * 1024 + o_[of] * 4 + sl_[of]) * 8);
        bf16x8 a[MC];
#pragma unroll
        for (int m = 0; m < MC; ++m) {
            int r = m * 16 + lr;
            int pr = 2 * r + (ks >> 3);
            int pc = lq + (ks & 7) * 4;
            a[m] = *(const bf16x8*)&inb[pr * 256 + ((pc ^ ((pr >> 1) & 7)) * 8)];
        }
#pragma unroll
        for (int of = 0; of < 2; ++of)
#pragma unroll
            for (int g = 0; g < 4; ++g)
#pragma unroll
                for (int m = 0; m < MC; ++m)
                    acc[m][of][g] = __builtin_amdgcn_mfma_f32_16x16x32_bf16(
                        a[m], bfr[of][g], acc[m][of][g], 0, 0, 0);
    }

#pragma unroll
    for (int m = 0; m < MC; ++m) {
#pragma unroll
        for (int of = 0; of < 2; ++of) {
            const int col = wid * 32 + of * 16 + lr;
            const float bi  = bp[col],       blf = bp[256 + col];
            const float brf = bp[512 + col], bu  = bp[768 + col];
#pragma unroll
            for (int j = 0; j < 4; ++j) {
                int row = m * 16 + lq * 4 + j;
                if (row < npo) {
                    float gi = fsig(acc[m][of][0][j] + bi);
                    float lf = fsig(acc[m][of][1][j] + blf);
                    float rf = fsig(acc[m][of][2][j] + brf);
                    float gu = ftanh(acc[m][of][3][j] + bu);
                    float lc = cprev[(size_t)(2 * row) * 256 + col];
                    float rc = cprev[(size_t)(2 * row + 1) * 256 + col];
                    float cv = gi * gu + lf * lc + rf * rc;
                    float hv = ftanh(cv);
                    if (LAST) {
                        dout[b * 256 + col] = cv;
                        dout[16384 + b * 256 + col] = hv;
                    } else {
                        cout_[row * 256 + col] = cv;
                        outb[row * 256 + (((col >> 3) ^ ((row >> 1) & 7)) * 8) + (col & 7)] = f2bf(hv);
                    }
                }
            }
        }
    }
}

__global__ __launch_bounds__(512, 1)
void tail_lstm(const ushort* __restrict__ hin,   // (8192,256) bf16: 64 x 128 nodes
               const float* __restrict__ cin,    // (8192,256) fp32
               const ushort* __restrict__ Wb,    // packed level weights
               const float* __restrict__ bp,     // (1024)
               float* __restrict__ cscr,         // 2 x 64 x 64 x 256 fp32 ping
               float* __restrict__ dout)
{
    __shared__ __align__(16) ushort P0[128 * 256];   // 64 KB
    __shared__ __align__(16) ushort P1[64 * 256];    // 32 KB

    const int b = blockIdx.x;
    const int tid = threadIdx.x;

    for (int ct = tid; ct < 4096; ct += 512) {
        int pr = ct >> 5, pc = ct & 31;
        bf16x8 v = *(const bf16x8*)(hin + ((size_t)(b * 128 + pr) * 256 + pc * 8));
        *(bf16x8*)&P0[pr * 256 + ((pc ^ ((pr >> 1) & 7)) * 8)] = v;
    }
    __syncthreads();

    float* c0p = cscr + (size_t)b * 64 * 256;
    float* c1p = cscr + (size_t)(64 + b) * 64 * 256;
    const float* cin_b = cin + (size_t)b * 128 * 256;

    tail_level<4, false>(P0, P1, Wb, bp, cin_b, c0p, nullptr, b, 64);
    __syncthreads();
    tail_level<2, false>(P1, P0, Wb, bp, c0p, c1p, nullptr, b, 32);
    __syncthreads();
    tail_level<1, false>(P0, P1, Wb, bp, c1p, c0p, nullptr, b, 16);
    __syncthreads();
    tail_level<1, false>(P1, P0, Wb, bp, c0p, c1p, nullptr, b, 8);
    __syncthreads();
    tail_level<1, false>(P0, P1, Wb, bp, c1p, c0p, nullptr, b, 4);
    __syncthreads();
    tail_level<1, false>(P1, P0, Wb, bp, c0p, c1p, nullptr, b, 2);
    __syncthreads();
    tail_level<1, true>(P0, P1, Wb, bp, c1p, nullptr, dout, b, 1);
}

// ---------------- host ----------------

extern "C" void kernel_launch(void* const* d_in, const int* in_sizes, int n_in,
                              void* d_out, int out_size, void* d_ws, size_t ws_size,
                              hipStream_t stream)
{
    const float* embs = (const float*)d_in[0];
    const float* Wcx  = (const float*)d_in[1];
    const float* bcx  = (const float*)d_in[2];
    const float* Wox  = (const float*)d_in[3];
    const float* box  = (const float*)d_in[4];
    const float* Wl   = (const float*)d_in[5];
    const float* bl   = (const float*)d_in[6];
    const float* Wr   = (const float*)d_in[7];
    const float* br   = (const float*)d_in[8];

    char* p = (char*)d_ws;
    ushort* Wb2 = (ushort*)p;  p += (size_t)524288 * 2;
    ushort* WbL = (ushort*)p;  p += (size_t)163840 * 2;
    float*  bp2 = (float*)p;   p += 1024 * 4;
    float*  bpL = (float*)p;   p += 512 * 4;
    float*  c0  = (float*)p;   p += (size_t)65536 * 256 * 4;   // 64 MB
    float*  cscr= (float*)p;                                    // reuses h0 (dead after L512)
    ushort* h0  = (ushort*)p;  p += (size_t)65536 * 256 * 2;   // 32 MB
    char* X = p;
    ushort* embsB = (ushort*)X;                                 // 40 MB (dead after leaf)
    float*  cA = (float*)X;                                     // 32 MB
    ushort* hA = (ushort*)(X + (size_t)32768 * 256 * 4);        // 16 MB
    float*  cB = (float*)(X + (size_t)48 * 1024 * 1024);        // 16 MB
    ushort* hB = (ushort*)(X + (size_t)64 * 1024 * 1024);       // 8 MB

    prep<<<1024, 256, 0, stream>>>(Wl, Wr, bl, br, Wcx, Wox, bcx, box, embs,
                                   Wb2, WbL, bp2, bpL, embsB);

    // leaf: (65536,320) @ (320, 2*256) -> c0 fp32, h0 bf16
    mfma_gemm<2, 10, 0><<<dim3(512, 4), 256, 0, stream>>>(
        embsB, WbL, bpL, nullptr, c0, h0, 65536);

    // out-np=512: in h0 (32768,512), c0 -> cA,hA
    mfma_gemm<4, 16, 1><<<dim3(256, 8), 256, 0, stream>>>(
        h0, Wb2, bp2, c0, cA, hA, 32768);
    // out-np=256: in hA (16384,512), cA -> cB,hB
    mfma_gemm<4, 16, 1><<<dim3(128, 8), 256, 0, stream>>>(
        hA, Wb2, bp2, cA, cB, hB, 16384);
    // out-np=128: in hB (8192,512), cB -> cA,hA
    mfma_gemm<4, 16, 1><<<dim3(64, 8), 256, 0, stream>>>(
        hB, Wb2, bp2, cB, cA, hA, 8192);

    // tail: out-np 64..1 (input hA (8192,256), cA); cscr reuses h0 region (dead)
    tail_lstm<<<64, 512, 0, stream>>>(
        hA, cA, Wb2, bp2, cscr, (float*)d_out);
}

// Round 10
// 260.298 us; speedup vs baseline: 15.4643x; 1.8147x over previous
//
#include <hip/hip_runtime.h>
#include <hip/hip_bf16.h>

// BinaryTreeLSTM  B=64, L=1024, IN_DIM=300, MEM=256 — v10.
// 8 launches: prep -> leaf -> L512 -> L256 -> L128 -> L64 -> L32 -> tail(16..1).
// Big-level GEMM = v6 core (verified). Tail rewritten: one dynamic 5-level
// loop (I-cache small), c in LDS, 2-stage register double-buffer on B-frag
// global loads (Wb2 L2-hot), h ping-pong in LDS with XOR chunk swizzle.

typedef __attribute__((ext_vector_type(8))) short bf16x8;
typedef __attribute__((ext_vector_type(4))) float f32x4;

__device__ __forceinline__ float fsig(float x)  { return 1.f / (1.f + __expf(-x)); }
__device__ __forceinline__ float ftanh(float x) { return 1.f - 2.f / (__expf(2.f * x) + 1.f); }
__device__ __forceinline__ ushort f2bf(float x) {
    __hip_bfloat16 b = __float2bfloat16(x);
    return *reinterpret_cast<ushort*>(&b);
}

__device__ __forceinline__ void gld_lds16(const void* g, void* l) {
    __builtin_amdgcn_global_load_lds((const __attribute__((address_space(1))) void*)g,
                                     (__attribute__((address_space(3))) void*)l, 16, 0, 0);
}

// ---------------- prep: pack level + pack leaf + biases + embs->bf16 ----------------
__global__ void prep(const float* __restrict__ Wl,  const float* __restrict__ Wr,
                     const float* __restrict__ bl,  const float* __restrict__ br,
                     const float* __restrict__ Wcx, const float* __restrict__ Wox,
                     const float* __restrict__ bcx, const float* __restrict__ box,
                     const float* __restrict__ embs,
                     ushort* __restrict__ Wb2, ushort* __restrict__ WbL,
                     float* __restrict__ bp2, float* __restrict__ bpL,
                     ushort* __restrict__ embsB)
{
    const int gid = blockIdx.x * 256 + threadIdx.x;     // 1024 blocks -> 262144
    for (int i = gid; i < 524288; i += 262144) {
        int e = i & 7, slot = (i >> 3) & 3, o = (i >> 5) & 255;
        int g = (i >> 13) & 3, t = i >> 15;
        int q = slot ^ ((o >> 1) & 3);
        int k = t * 32 + q * 8 + e;
        float v = (k < 256) ? Wl[(g * 256 + o) * 256 + k]
                            : Wr[(g * 256 + o) * 256 + (k - 256)];
        Wb2[i] = f2bf(v);
    }
    if (gid < 163840) {
        int e = gid & 7, slot = (gid >> 3) & 3, o = (gid >> 5) & 255;
        int g = (gid >> 13) & 1, t = gid >> 14;
        int q = slot ^ ((o >> 1) & 3);
        int k = t * 32 + q * 8 + e;
        float v = 0.f;
        if (k < 300) v = g ? Wox[o * 300 + k] : Wcx[o * 300 + k];
        WbL[gid] = f2bf(v);
    }
    if (gid < 1024) bp2[gid] = bl[gid] + br[gid];
    if (gid < 512) {
        int g = gid >> 8, o = gid & 255;
        bpL[gid] = g ? box[o] : bcx[o];
    }
    for (int i = gid; i < 65536 * 80; i += 262144) {
        int row = i / 80;
        int k = (i - row * 80) * 4;
        float4 v = make_float4(0.f, 0.f, 0.f, 0.f);
        if (k < 300) v = *(const float4*)(embs + (size_t)row * 300 + k);
        ushort4 o4;
        o4.x = f2bf(v.x); o4.y = f2bf(v.y); o4.z = f2bf(v.z); o4.w = f2bf(v.w);
        *(ushort4*)(embsB + (size_t)row * 320 + k) = o4;
    }
}

// ---------------- v6 big-level GEMM (verified) ----------------
template<int NG, int HALVES, int MODE>
__global__ __launch_bounds__(256, 4)
void mfma_gemm(const ushort* __restrict__ A,
               const ushort* __restrict__ Wb,
               const float* __restrict__ bp,
               const float* __restrict__ Cprev,
               float* __restrict__ c_out,
               ushort* __restrict__ h_out,
               int M)
{
    constexpr int K = HALVES * 32;
    constexpr int OW = 128 / NG;
    __shared__ __align__(16) ushort As[2][512 * 8];
    __shared__ __align__(16) ushort Bs[2][512 * 8];

    const int tid = threadIdx.x;
    const int wid = tid >> 6, ln = tid & 63;
    const int lq = ln >> 4, lr = ln & 15;
    const int wm = wid >> 1, wn = wid & 1;
    const int rowBlk = blockIdx.x * 128;
    const int o0 = blockIdx.y * OW;

    f32x4 acc[4][4];
#pragma unroll
    for (int m = 0; m < 4; ++m)
#pragma unroll
        for (int f = 0; f < 4; ++f) acc[m][f] = f32x4{0.f, 0.f, 0.f, 0.f};

    const int ar0 = tid >> 2,  as0 = tid & 3;
    const int ar1 = ar0 + 64;
    const int aq0 = (as0 - ((ar0 >> 1) & 3)) & 3;
    const int aq1 = (as0 - ((ar1 >> 1) & 3)) & 3;
    const ushort* aP0 = A + (size_t)min(rowBlk + ar0, M - 1) * K + aq0 * 8;
    const ushort* aP1 = A + (size_t)min(rowBlk + ar1, M - 1) * K + aq1 * 8;
    const int bj0 = tid >> 2,        bs0 = tid & 3;
    const int bj1 = (tid + 256) >> 2;
    const int bg0 = bj0 / OW, bo0 = o0 + (bj0 & (OW - 1));
    const int bg1 = bj1 / OW, bo1 = o0 + (bj1 & (OW - 1));
    const ushort* bP0 = Wb + ((size_t)bg0 * 1024 + bo0 * 4 + bs0) * 8;
    const ushort* bP1 = Wb + ((size_t)bg1 * 1024 + bo1 * 4 + bs0) * 8;
    constexpr size_t BSTR = (size_t)NG * 1024 * 8;

    const int aSw = (lq + ((lr >> 1) & 3)) & 3;
    const int bSw = lq ^ ((lr >> 1) & 3);
    int aOff[4];
#pragma unroll
    for (int m = 0; m < 4; ++m)
        aOff[m] = ((wm * 64 + m * 16 + lr) * 4 + aSw) * 8;
    int bOff[4];
#pragma unroll
    for (int f = 0; f < 4; ++f)
        bOff[f] = ((f * 32 + wn * 16 + lr) * 4 + bSw) * 8;

    gld_lds16(aP0, &As[0][tid * 8]);
    gld_lds16(aP1, &As[0][(tid + 256) * 8]);
    gld_lds16(bP0, &Bs[0][tid * 8]);
    gld_lds16(bP1, &Bs[0][(tid + 256) * 8]);

#pragma unroll
    for (int h = 0; h < HALVES; ++h) {
        __syncthreads();
        const int cur = h & 1;
        if (h + 1 < HALVES) {
            gld_lds16(aP0 + (size_t)(h + 1) * 32, &As[cur ^ 1][tid * 8]);
            gld_lds16(aP1 + (size_t)(h + 1) * 32, &As[cur ^ 1][(tid + 256) * 8]);
            gld_lds16(bP0 + (size_t)(h + 1) * BSTR, &Bs[cur ^ 1][tid * 8]);
            gld_lds16(bP1 + (size_t)(h + 1) * BSTR, &Bs[cur ^ 1][(tid + 256) * 8]);
        }
        bf16x8 a[4];
#pragma unroll
        for (int m = 0; m < 4; ++m)
            a[m] = *(const bf16x8*)&As[cur][aOff[m]];
#pragma unroll
        for (int f = 0; f < 4; ++f) {
            bf16x8 b = *(const bf16x8*)&Bs[cur][bOff[f]];
#pragma unroll
            for (int m = 0; m < 4; ++m)
                acc[m][f] = __builtin_amdgcn_mfma_f32_16x16x32_bf16(a[m], b, acc[m][f], 0, 0, 0);
        }
    }

#pragma unroll
    for (int m = 0; m < 4; ++m) {
        const int row0 = rowBlk + wm * 64 + m * 16 + lq * 4;
        if constexpr (MODE == 0) {
#pragma unroll
            for (int ob = 0; ob < 2; ++ob) {
                const int col = o0 + ob * 32 + wn * 16 + lr;
                const float bc = bp[col], bo = bp[256 + col];
#pragma unroll
                for (int j = 0; j < 4; ++j) {
                    int row = row0 + j;
                    if (row < M) {
                        float cv = acc[m][ob][j] + bc;
                        float ov = acc[m][2 + ob][j] + bo;
                        c_out[(size_t)row * 256 + col] = cv;
                        h_out[(size_t)row * 256 + col] = f2bf(fsig(ov) * ftanh(cv));
                    }
                }
            }
        } else {
            const int col = o0 + wn * 16 + lr;
            const float bi  = bp[col],       blf = bp[256 + col];
            const float brf = bp[512 + col], bu  = bp[768 + col];
#pragma unroll
            for (int j = 0; j < 4; ++j) {
                int row = row0 + j;
                if (row < M) {
                    float gi = fsig(acc[m][0][j] + bi);
                    float lf = fsig(acc[m][1][j] + blf);
                    float rf = fsig(acc[m][2][j] + brf);
                    float gu = ftanh(acc[m][3][j] + bu);
                    float lc = Cprev[(size_t)row * 512 + col];
                    float rc = Cprev[(size_t)row * 512 + 256 + col];
                    float cv = gi * gu + lf * lc + rf * rc;
                    c_out[(size_t)row * 256 + col] = cv;
                    h_out[(size_t)row * 256 + col] = f2bf(ftanh(cv));
                }
            }
        }
    }
}

// ---------------- tail: out-np 16..1, one block per batch, 512 threads ----------------
// 5 levels in a dynamic loop. h AND c both in LDS. Wave w owns o-cols
// [32w,32w+32) x 4 gates. B-frags: 2-stage register double-buffer from
// packed Wb2 (L2-hot). acc[2][4] = 32 VGPR, bfr 2x8x4 = 64 VGPR.

__global__ __launch_bounds__(512, 1)
void tail_lstm(const ushort* __restrict__ hin,   // (2048,256) bf16: 64 x 32 nodes
               const float* __restrict__ cin,    // (2048,256) fp32
               const ushort* __restrict__ Wb,    // packed level weights
               const float* __restrict__ bp,     // (1024)
               float* __restrict__ dout)
{
    __shared__ __align__(16) ushort H0[32 * 256];   // 16 KB
    __shared__ __align__(16) ushort H1[16 * 256];   //  8 KB
    __shared__ __align__(16) float  C0[32 * 256];   // 32 KB
    __shared__ __align__(16) float  C1[16 * 256];   // 16 KB

    const int b = blockIdx.x;
    const int tid = threadIdx.x;
    const int wid = tid >> 6, ln = tid & 63;
    const int lq = ln >> 4, lr = ln & 15;

    // ---- cooperative load: h (32x256 bf16, swizzled) + c (32x256 f32, linear)
    for (int ct = tid; ct < 1024; ct += 512) {
        int pr = ct >> 5, pc = ct & 31;
        bf16x8 v = *(const bf16x8*)(hin + ((size_t)(b * 32 + pr) * 256 + pc * 8));
        *(bf16x8*)&H0[pr * 256 + ((pc ^ ((pr >> 1) & 7)) * 8)] = v;
    }
    for (int i = tid; i < 2048; i += 512)
        *(float4*)&C0[i * 4] = *(const float4*)(cin + (size_t)b * 32 * 256 + i * 4);
    __syncthreads();

    // per-lane B addressing (constant across levels)
    int o_[2], sl_[2];
    const ushort* bB[2];
#pragma unroll
    for (int of = 0; of < 2; ++of) {
        o_[of] = wid * 32 + of * 16 + lr;
        sl_[of] = lq ^ ((o_[of] >> 1) & 3);
        bB[of] = Wb + (size_t)(o_[of] * 4 + sl_[of]) * 8;
    }
    const float bi  = bp[o_[0]],       blf = bp[256 + o_[0]];
    const float brf = bp[512 + o_[0]], bu  = bp[768 + o_[0]];
    const float bi1  = bp[o_[1]],       blf1 = bp[256 + o_[1]];
    const float brf1 = bp[512 + o_[1]], bu1  = bp[768 + o_[1]];

#pragma unroll 1
    for (int lvl = 0; lvl < 5; ++lvl) {
        const int npo = 16 >> lvl;
        const ushort* Hin = (lvl & 1) ? H1 : H0;
        ushort*       Hout = (lvl & 1) ? H0 : H1;
        const float*  Cin = (lvl & 1) ? C1 : C0;
        float*        Cout = (lvl & 1) ? C0 : C1;

        f32x4 acc[2][4];
#pragma unroll
        for (int of = 0; of < 2; ++of)
#pragma unroll
            for (int g = 0; g < 4; ++g) acc[of][g] = f32x4{0.f, 0.f, 0.f, 0.f};

        bf16x8 b0[2][4], b1[2][4], a0, a1;
        // stage ks=0
#pragma unroll
        for (int of = 0; of < 2; ++of)
#pragma unroll
            for (int g = 0; g < 4; ++g)
                b0[of][g] = *(const bf16x8*)(bB[of] + (size_t)g * 8192);
        {
            int pr = 2 * lr, pc = lq;
            a0 = *(const bf16x8*)&Hin[pr * 256 + ((pc ^ ((pr >> 1) & 7)) * 8)];
        }

#pragma unroll 1
        for (int ks = 0; ks < 16; ks += 2) {
            // prefetch ks+1 into b1/a1
            if (ks + 1 < 16) {
#pragma unroll
                for (int of = 0; of < 2; ++of)
#pragma unroll
                    for (int g = 0; g < 4; ++g)
                        b1[of][g] = *(const bf16x8*)(bB[of] + (size_t)((ks + 1) * 4 + g) * 8192);
                int pr = 2 * lr + ((ks + 1) >> 3), pc = lq + ((ks + 1) & 7) * 4;
                a1 = *(const bf16x8*)&Hin[pr * 256 + ((pc ^ ((pr >> 1) & 7)) * 8)];
            }
#pragma unroll
            for (int of = 0; of < 2; ++of)
#pragma unroll
                for (int g = 0; g < 4; ++g)
                    acc[of][g] = __builtin_amdgcn_mfma_f32_16x16x32_bf16(a0, b0[of][g], acc[of][g], 0, 0, 0);
            // prefetch ks+2 into b0/a0
            if (ks + 2 < 16) {
#pragma unroll
                for (int of = 0; of < 2; ++of)
#pragma unroll
                    for (int g = 0; g < 4; ++g)
                        b0[of][g] = *(const bf16x8*)(bB[of] + (size_t)((ks + 2) * 4 + g) * 8192);
                int pr = 2 * lr + ((ks + 2) >> 3), pc = lq + ((ks + 2) & 7) * 4;
                a0 = *(const bf16x8*)&Hin[pr * 256 + ((pc ^ ((pr >> 1) & 7)) * 8)];
            }
#pragma unroll
            for (int of = 0; of < 2; ++of)
#pragma unroll
                for (int g = 0; g < 4; ++g)
                    acc[of][g] = __builtin_amdgcn_mfma_f32_16x16x32_bf16(a1, b1[of][g], acc[of][g], 0, 0, 0);
        }

        // epilogue
#pragma unroll
        for (int of = 0; of < 2; ++of) {
            const int col = o_[of];
            const float vbi  = of ? bi1 : bi,   vblf = of ? blf1 : blf;
            const float vbrf = of ? brf1 : brf, vbu  = of ? bu1 : bu;
#pragma unroll
            for (int j = 0; j < 4; ++j) {
                int row = lq * 4 + j;
                if (row < npo) {
                    float gi = fsig(acc[of][0][j] + vbi);
                    float lf = fsig(acc[of][1][j] + vblf);
                    float rf = fsig(acc[of][2][j] + vbrf);
                    float gu = ftanh(acc[of][3][j] + vbu);
                    float lc = Cin[(2 * row) * 256 + col];
                    float rc = Cin[(2 * row + 1) * 256 + col];
                    float cv = gi * gu + lf * lc + rf * rc;
                    float hv = ftanh(cv);
                    if (lvl == 4) {
                        dout[b * 256 + col] = cv;
                        dout[16384 + b * 256 + col] = hv;
                    } else {
                        Cout[row * 256 + col] = cv;
                        Hout[row * 256 + (((col >> 3) ^ ((row >> 1) & 7)) * 8) + (col & 7)] = f2bf(hv);
                    }
                }
            }
        }
        __syncthreads();
    }
}

// ---------------- host ----------------

extern "C" void kernel_launch(void* const* d_in, const int* in_sizes, int n_in,
                              void* d_out, int out_size, void* d_ws, size_t ws_size,
                              hipStream_t stream)
{
    const float* embs = (const float*)d_in[0];
    const float* Wcx  = (const float*)d_in[1];
    const float* bcx  = (const float*)d_in[2];
    const float* Wox  = (const float*)d_in[3];
    const float* box  = (const float*)d_in[4];
    const float* Wl   = (const float*)d_in[5];
    const float* bl   = (const float*)d_in[6];
    const float* Wr   = (const float*)d_in[7];
    const float* br   = (const float*)d_in[8];

    char* p = (char*)d_ws;
    ushort* Wb2 = (ushort*)p;  p += (size_t)524288 * 2;
    ushort* WbL = (ushort*)p;  p += (size_t)163840 * 2;
    float*  bp2 = (float*)p;   p += 1024 * 4;
    float*  bpL = (float*)p;   p += 512 * 4;
    float*  c0  = (float*)p;   p += (size_t)65536 * 256 * 4;   // 64 MB
    ushort* h0  = (ushort*)p;  p += (size_t)65536 * 256 * 2;   // 32 MB
    char* X = p;
    ushort* embsB = (ushort*)X;                                 // 40 MB (dead after leaf)
    float*  cA = (float*)X;                                     // 32 MB
    ushort* hA = (ushort*)(X + (size_t)32768 * 256 * 4);        // 16 MB
    float*  cB = (float*)(X + (size_t)48 * 1024 * 1024);        // 16 MB
    ushort* hB = (ushort*)(X + (size_t)64 * 1024 * 1024);       // 8 MB

    prep<<<1024, 256, 0, stream>>>(Wl, Wr, bl, br, Wcx, Wox, bcx, box, embs,
                                   Wb2, WbL, bp2, bpL, embsB);

    // leaf: (65536,320) @ (320, 2*256) -> c0 fp32, h0 bf16
    mfma_gemm<2, 10, 0><<<dim3(512, 4), 256, 0, stream>>>(
        embsB, WbL, bpL, nullptr, c0, h0, 65536);

    // np=512: h0 (32768,512), c0 -> cA,hA (M=32768)
    mfma_gemm<4, 16, 1><<<dim3(256, 8), 256, 0, stream>>>(
        h0, Wb2, bp2, c0, cA, hA, 32768);
    // np=256: hA, cA -> cB,hB (M=16384)
    mfma_gemm<4, 16, 1><<<dim3(128, 8), 256, 0, stream>>>(
        hA, Wb2, bp2, cA, cB, hB, 16384);
    // np=128: hB, cB -> cA,hA (M=8192)
    mfma_gemm<4, 16, 1><<<dim3(64, 8), 256, 0, stream>>>(
        hB, Wb2, bp2, cB, cA, hA, 8192);
    // np=64: hA, cA -> cB,hB (M=4096)
    mfma_gemm<4, 16, 1><<<dim3(32, 8), 256, 0, stream>>>(
        hA, Wb2, bp2, cA, cB, hB, 4096);
    // np=32: hB, cB -> cA,hA (M=2048)
    mfma_gemm<4, 16, 1><<<dim3(16, 8), 256, 0, stream>>>(
        hB, Wb2, bp2, cB, cA, hA, 2048);

    // tail: np 16..1 (input hA (2048,256), cA (2048,256)) -> d_out
    tail_lstm<<<64, 512, 0, stream>>>(
        hA, cA, Wb2, bp2, (float*)d_out);
}